// Round 4
// baseline (1930.428 us; speedup 1.0000x reference)
//
#include <hip/hip_runtime.h>

typedef unsigned short u16;
typedef __attribute__((ext_vector_type(8))) short bfrag8;   // 8 x bf16 (4 VGPRs)
typedef __attribute__((ext_vector_type(4))) float f32x4;

// ---------- bf16 helpers ----------
__device__ __forceinline__ float b2f(u16 u){ union { unsigned ui; float f; } v; v.ui = ((unsigned)u) << 16; return v.f; }
__device__ __forceinline__ u16 f2b(float f){ union { float f; unsigned ui; } v; v.f = f; unsigned r = (v.ui + 0x7FFF + ((v.ui >> 16) & 1)) >> 16; return (u16)r; }

// ---------- zero ----------
__global__ __launch_bounds__(256) void zero_f32(float* p, int n){
  int i = blockIdx.x*256 + threadIdx.x;
  if (i < n) p[i] = 0.f;
}

// ---------- transpose f32: W (KxN) -> Wt (NxK) ----------
__global__ __launch_bounds__(256) void transpose_f32(const float* __restrict__ W, float* __restrict__ Wt, int K, int N){
  __shared__ float tile[32][33];
  int bx = blockIdx.x * 32;   // n base
  int by = blockIdx.y * 32;   // k base
  int tx = threadIdx.x & 31;
  int ty = threadIdx.x >> 5;  // 0..7
  #pragma unroll
  for (int i = 0; i < 32; i += 8)
    tile[ty+i][tx] = W[(size_t)(by+ty+i)*N + bx+tx];
  __syncthreads();
  #pragma unroll
  for (int i = 0; i < 32; i += 8)
    Wt[(size_t)(bx+ty+i)*K + by+tx] = tile[tx][ty+i];
}

// ---------- split staging: 8 f32 -> up to 3 bf16 planes in LDS ----------
template<int NS>
__device__ __forceinline__ void stage_split(u16* lds, int off, const float* __restrict__ src){
  float v[8];
  *(float4*)v       = *(const float4*)src;
  *(float4*)(v + 4) = *(const float4*)(src + 4);
  u16 p0[8], p1[8], p2[8];
  #pragma unroll
  for (int i = 0; i < 8; ++i){
    u16 a = f2b(v[i]); p0[i] = a;
    if constexpr (NS > 1){
      float r = v[i] - b2f(a);
      u16 bq = f2b(r); p1[i] = bq;
      if constexpr (NS > 2){
        float r2 = r - b2f(bq);
        p2[i] = f2b(r2);
      }
    }
  }
  *(uint4*)(lds + off) = *(uint4*)p0;
  if constexpr (NS > 1) *(uint4*)(lds + 4096 + off) = *(uint4*)p1;
  if constexpr (NS > 2) *(uint4*)(lds + 8192 + off) = *(uint4*)p2;
}

// ---------- split GEMM: C(MxN) = A(MxK f32, stride lda) @ Bt(NxK f32)^T + bias ----------
// NPROD: 6 (3-split, ~f32 exact), 3 (2-split), 1 (plain bf16).
// MODE 0: qkv epilogue (col<1024 -> Cq f32, <2048 -> Ck f32, else Cv bf16), MODE 1: Cf f32.
template<int NPROD, int MODE>
__global__ __launch_bounds__(256) void gemm_split(
    const float* __restrict__ A, int lda,
    const float* __restrict__ Bt, int bn_off,
    const float* __restrict__ bias,
    float* __restrict__ Cq, float* __restrict__ Ck, u16* __restrict__ Cv,
    float* __restrict__ Cf, int M, int N, int K)
{
  constexpr int NSA = (NPROD==6) ? 3 : (NPROD==3) ? 2 : 1;
  constexpr int NSB = NSA;
  __shared__ __align__(16) u16 As[NSA*4096];
  __shared__ __align__(16) u16 Bs[NSB*4096];
  int tid = threadIdx.x;
  int lane = tid & 63;
  int wave = tid >> 6;
  int wm = wave >> 1, wn = wave & 1;
  int bm = blockIdx.y * 128, bn = blockIdx.x * 128;
  f32x4 acc[4][4];
  #pragma unroll
  for (int i=0;i<4;i++)
    #pragma unroll
    for (int j=0;j<4;j++)
      #pragma unroll
      for (int r=0;r<4;r++) acc[i][j][r] = 0.f;
  int mr = lane & 15;
  int kq = (lane >> 4) * 8;
  for (int k0 = 0; k0 < K; k0 += 32) {
    #pragma unroll
    for (int v = 0; v < 2; ++v) {
      int idx = tid + v*256;            // 0..511 vec8 slots
      int row = idx >> 2;               // 0..127
      int col = (idx & 3) * 8;          // 0,8,16,24
      stage_split<NSA>(As, row*32 + col, &A [(size_t)(bm+row)*lda + k0 + col]);
      stage_split<NSB>(Bs, row*32 + col, &Bt[(size_t)(bn_off+bn+row)*K + k0 + col]);
    }
    __syncthreads();
    bfrag8 af[NSA][4], bf[NSB][4];
    #pragma unroll
    for (int s=0;s<NSA;s++)
      #pragma unroll
      for (int i=0;i<4;i++) af[s][i] = *(const bfrag8*)(&As[s*4096 + (wm*64 + i*16 + mr)*32 + kq]);
    #pragma unroll
    for (int s=0;s<NSB;s++)
      #pragma unroll
      for (int j=0;j<4;j++) bf[s][j] = *(const bfrag8*)(&Bs[s*4096 + (wn*64 + j*16 + mr)*32 + kq]);
#define MM(sa,sb) \
    { _Pragma("unroll") for (int i=0;i<4;i++){ _Pragma("unroll") for (int j=0;j<4;j++){ \
        acc[i][j] = __builtin_amdgcn_mfma_f32_16x16x32_bf16(af[sa][i], bf[sb][j], acc[i][j], 0, 0, 0); } } }
    if constexpr (NPROD == 6){ MM(0,2) MM(1,1) MM(2,0) MM(0,1) MM(1,0) }
    if constexpr (NPROD == 3){ MM(0,1) MM(1,0) }
    MM(0,0)
#undef MM
    __syncthreads();
  }
  // C/D layout: col = lane&15, row = (lane>>4)*4 + reg  [m89/m91-verified]
  #pragma unroll
  for (int i=0;i<4;i++){
    #pragma unroll
    for (int j=0;j<4;j++){
      int col = bn_off + bn + wn*64 + j*16 + (lane & 15);
      float bv = bias[col];
      #pragma unroll
      for (int r=0;r<4;r++){
        int row = bm + wm*64 + i*16 + (lane>>4)*4 + r;
        float val = acc[i][j][r] + bv;
        if constexpr (MODE == 0){
          if (col < 1024)      Cq[(size_t)row*1024 + col]        = val;
          else if (col < 2048) Ck[(size_t)row*1024 + (col-1024)] = val;
          else                 Cv[(size_t)row*1024 + (col-2048)] = f2b(val);
        } else {
          Cf[(size_t)row*N + col] = val;
        }
      }
    }
  }
}

// ---------- per-d constants ----------
struct __align__(16) ConsT { int b1; float sg1; int b2; float sg2; };

// Per-token feature computation, lane-per-token, f32 tile (stride 65).
__device__ __forceinline__ void token_feats(const float* tile, int tok,
    const ConsT* cons, const float* oms, float s_node, float sqrt2s, float pscale,
    float* poly, float* prf)
{
  const float* tp = tile + tok*65;
  float sq = 0.f;
  for (int d = 0; d < 64; ++d) { float u = tp[d]; sq += u*u; }
  float sc = 1.f / fmaxf(sqrtf(sq), 1e-6f);
  float cs1[16], cs2[16], pm[8];
  #pragma unroll
  for (int p=0;p<16;p++){ cs1[p]=0.f; cs2[p]=0.f; }
  #pragma unroll
  for (int m=0;m<8;m++) pm[m]=0.f;
  for (int d = 0; d < 64; ++d) {
    float un = tp[d] * sc;
    ConsT cc = cons[d];
    float v1 = un*cc.sg1, v2 = un*cc.sg2;
    #pragma unroll
    for (int p=0;p<16;p++){
      cs1[p] += (cc.b1==p) ? v1 : 0.f;
      cs2[p] += (cc.b2==p) ? v2 : 0.f;
    }
    #pragma unroll
    for (int m=0;m<8;m++) pm[m] += un * oms[d*8 + m];
  }
  #pragma unroll
  for (int p=0;p<16;p++){
    float s = 0.f;
    #pragma unroll
    for (int a=0;a<16;a++) s += cs1[a]*cs2[(p-a)&15];
    poly[p] = s * 0.25f;   // irfft(rfft*rfft, n=16)/sqrt(16) = circ-conv / 4
  }
  #pragma unroll
  for (int m=0;m<8;m++){
    float e = fminf(fmaxf(pm[m]*sqrt2s - s_node, -10.f), 10.f);
    prf[m] = expf(e) * pscale;
  }
}

// ---------- K-path: features + kv (128x64) + ksum accumulation ----------
__global__ __launch_bounds__(256) void kfeat_kv(const float* __restrict__ kf, const u16* __restrict__ vb,
    const float* __restrict__ omega, const float* __restrict__ qn, const float* __restrict__ qw,
    const int* __restrict__ h1, const int* __restrict__ s1,
    const int* __restrict__ h2, const int* __restrict__ s2,
    float* __restrict__ kv, float* __restrict__ ksum)
{
  __shared__ float ktile[64*65];
  __shared__ __align__(16) float vtile[64*64];
  __shared__ float feat[64*129];
  __shared__ float oms[64*8];
  __shared__ ConsT cons[64];
  int tid = threadIdx.x, lane = tid & 63, wave = tid >> 6;
  int bh = blockIdx.y, b = bh >> 4, h = bh & 15;
  int chunk = blockIdx.x;                 // 0..7, 512 tokens each
  if (tid < 64) {
    ConsT c; c.b1 = h1[tid]; c.sg1 = (float)s1[tid]; c.b2 = h2[tid]; c.sg2 = (float)s2[tid];
    cons[tid] = c;
  }
  for (int i = tid; i < 512; i += 256) oms[i] = omega[h*512 + i];
  float s_node = qn[0];
  float sqrt2s = sqrtf(2.f * fmaxf(s_node, 0.f));
  float pscale = 0.35355339059327373f * sqrtf(fmaxf(qw[0], 0.f));
  f32x4 acc4[8];
  #pragma unroll
  for (int q=0;q<8;q++)
    #pragma unroll
    for (int r=0;r<4;r++) acc4[q][r] = 0.f;
  float ks = 0.f;
  int f_own = tid >> 1, d0 = (tid & 1) * 32;
  int tokA = wave*16 + (lane & 15);       // 4x redundant; writes guarded by lane<16
  for (int sub = 0; sub < 8; ++sub) {
    int base = chunk*512 + sub*64;
    __syncthreads();                      // protect tile overwrite vs prev accumulate reads
    for (int idx = tid; idx < 4096; idx += 256) {
      int t = idx >> 6, d = idx & 63;
      size_t g = (size_t)(b*4096 + base + t)*1024 + h*64 + d;
      ktile[t*65 + d] = kf[g];
      vtile[t*64 + d] = b2f(vb[g]);
    }
    __syncthreads();                      // tiles + consts ready
    {
      float poly[16], prf[8];
      token_feats(ktile, tokA, cons, oms, s_node, sqrt2s, pscale, poly, prf);
      if (lane < 16) {
        #pragma unroll
        for (int f = 0; f < 128; ++f)
          feat[tokA*129 + f] = poly[f>>3] * prf[f&7];
      }
    }
    __syncthreads();                      // feat ready
    for (int t = 0; t < 64; ++t) {
      float a = feat[t*129 + f_own];
      if (!(tid & 1)) ks += a;
      const f32x4* vp = (const f32x4*)(&vtile[t*64 + d0]);
      #pragma unroll
      for (int q=0;q<8;q++) acc4[q] += vp[q] * a;
    }
  }
  size_t kvb = ((size_t)bh*128 + f_own)*64 + d0;
  #pragma unroll
  for (int q=0;q<8;q++)
    #pragma unroll
    for (int r=0;r<4;r++)
      atomicAdd(&kv[kvb + q*4 + r], acc4[q][r]);
  if (!(tid & 1)) atomicAdd(&ksum[bh*128 + f_own], ks);
}

// ---------- Q-path: features fused with context/norm; writes attn (f32) over the q buffer ----------
__global__ __launch_bounds__(256) void qfeat_ctx(float* qf,
    const float* __restrict__ omega, const float* __restrict__ qn, const float* __restrict__ qw,
    const int* __restrict__ h1, const int* __restrict__ s1,
    const int* __restrict__ h2, const int* __restrict__ s2,
    const float* __restrict__ kv, const float* __restrict__ ksum)
{
  __shared__ float kvs[128*64];
  __shared__ float ksums[128];
  __shared__ float qtile[64*65];
  __shared__ float feat[64*129];
  __shared__ float nrm_s[64];
  __shared__ float oms[64*8];
  __shared__ ConsT cons[64];
  int tid = threadIdx.x, lane = tid & 63, wave = tid >> 6;
  int bh = blockIdx.y, b = bh >> 4, h = bh & 15;
  int chunk = blockIdx.x;                 // 0..7, 512 tokens each
  if (tid < 64) {
    ConsT c; c.b1 = h1[tid]; c.sg1 = (float)s1[tid]; c.b2 = h2[tid]; c.sg2 = (float)s2[tid];
    cons[tid] = c;
  }
  for (int i = tid; i < 512; i += 256) oms[i] = omega[h*512 + i];
  for (int i = tid; i < 8192; i += 256) kvs[i] = kv[(size_t)bh*8192 + i];
  if (tid < 128) ksums[tid] = ksum[bh*128 + tid];
  float s_node = qn[0];
  float sqrt2s = sqrtf(2.f * fmaxf(s_node, 0.f));
  float pscale = 0.35355339059327373f * sqrtf(fmaxf(qw[0], 0.f));
  int tokA = wave*16 + (lane & 15);
  for (int sub = 0; sub < 8; ++sub) {
    int base = chunk*512 + sub*64;
    for (int idx = tid; idx < 4096; idx += 256) {   // stage qtile
      int t = idx >> 6, d = idx & 63;
      qtile[t*65 + d] = qf[(size_t)(b*4096 + base + t)*1024 + h*64 + d];
    }
    __syncthreads();                      // qtile + staged consts ready; prev phase-B done
    {
      float poly[16], prf[8];
      token_feats(qtile, tokA, cons, oms, s_node, sqrt2s, pscale, poly, prf);
      if (lane < 16) {
        float nv = 0.f;
        #pragma unroll
        for (int f = 0; f < 128; ++f) {
          float qff = poly[f>>3] * prf[f&7];
          feat[tokA*129 + f] = qff;
          nv += qff * ksums[f];
        }
        nrm_s[tokA] = nv;
      }
    }
    __syncthreads();                      // feat + nrm ready
    for (int j = 0; j < 16; ++j) {        // phase B: wave-per-token context
      int tl = wave*16 + j;
      float nrm = nrm_s[tl];
      float ctx = 0.f;
      #pragma unroll 16
      for (int f = 0; f < 128; ++f)
        ctx += feat[tl*129 + f] * kvs[f*64 + lane];
      qf[(size_t)(b*4096 + base + tl)*1024 + h*64 + lane] = ctx / fmaxf(nrm, 1e-4f);
    }
    __syncthreads();                      // phase-B reads done before next-iter feat writes
  }
}

// ---------- launch ----------
extern "C" void kernel_launch(void* const* d_in, const int* in_sizes, int n_in,
                              void* d_out, int out_size, void* d_ws, size_t ws_size,
                              hipStream_t stream)
{
  const float* x     = (const float*)d_in[0];
  const float* qkv_w = (const float*)d_in[1];
  const float* qkv_b = (const float*)d_in[2];
  const float* out_w = (const float*)d_in[3];
  const float* out_b = (const float*)d_in[4];
  const float* omega = (const float*)d_in[5];
  const float* qn    = (const float*)d_in[6];
  const float* qw    = (const float*)d_in[7];
  const int* h1 = (const int*)d_in[8];
  const int* s1 = (const int*)d_in[9];
  const int* h2 = (const int*)d_in[10];
  const int* s2 = (const int*)d_in[11];

  // ws layout (~178 MB): q f32 (later attn) | k f32 | v bf16 | wT1 f32 | wT2 f32 | kv | ksum
  const size_t SZ_Q   = (size_t)16384*1024*4;   // 64 MB
  const size_t SZ_K   = (size_t)16384*1024*4;   // 64 MB
  const size_t SZ_V   = (size_t)16384*1024*2;   // 32 MB
  const size_t SZ_WT1 = (size_t)3072*1024*4;    // 12 MB
  const size_t SZ_WT2 = (size_t)1024*1024*4;    //  4 MB
  const size_t SZ_KV  = (size_t)64*128*64*4;    //  2 MB
  char* ws = (char*)d_ws;
  float* qf  = (float*)ws;
  float* kf  = (float*)(ws + SZ_Q);
  u16*   vb  = (u16*)  (ws + SZ_Q + SZ_K);
  float* wT1 = (float*)(ws + SZ_Q + SZ_K + SZ_V);
  float* wT2 = (float*)(ws + SZ_Q + SZ_K + SZ_V + SZ_WT1);
  float* kvp = (float*)(ws + SZ_Q + SZ_K + SZ_V + SZ_WT1 + SZ_WT2);
  float* ksp = (float*)(ws + SZ_Q + SZ_K + SZ_V + SZ_WT1 + SZ_WT2 + SZ_KV);

  int nz = (int)((SZ_KV + (size_t)64*128*4) / 4);
  zero_f32<<<(nz+255)/256, 256, 0, stream>>>(kvp, nz);
  transpose_f32<<<dim3(3072/32, 1024/32), 256, 0, stream>>>(qkv_w, wT1, 1024, 3072);
  transpose_f32<<<dim3(1024/32, 1024/32), 256, 0, stream>>>(out_w, wT2, 1024, 1024);
  // q,k columns (0..2047): 3-split, ~f32-exact
  gemm_split<6,0><<<dim3(16, 128), 256, 0, stream>>>(x, 1024, wT1, 0, qkv_b,
      qf, kf, vb, (float*)nullptr, 16384, 3072, 1024);
  // v columns (2048..3071): plain bf16
  gemm_split<1,0><<<dim3(8, 128), 256, 0, stream>>>(x, 1024, wT1, 2048, qkv_b,
      qf, kf, vb, (float*)nullptr, 16384, 3072, 1024);
  kfeat_kv<<<dim3(8, 64), 256, 0, stream>>>(kf, vb, omega, qn, qw, h1, s1, h2, s2, kvp, ksp);
  qfeat_ctx<<<dim3(8, 64), 256, 0, stream>>>(qf, omega, qn, qw, h1, s1, h2, s2, kvp, ksp);
  // out = attn(=qf) @ out_w + out_b : 2-split
  gemm_split<3,1><<<dim3(8, 128), 256, 0, stream>>>(qf, 1024, wT2, 0, out_b,
      (float*)nullptr, (float*)nullptr, (u16*)nullptr, (float*)d_out, 16384, 1024, 1024);
}

// Round 5
// 955.931 us; speedup vs baseline: 2.0194x; 2.0194x over previous
//
#include <hip/hip_runtime.h>

typedef unsigned short u16;
typedef __attribute__((ext_vector_type(8))) short bfrag8;   // 8 x bf16 (4 VGPRs)
typedef __attribute__((ext_vector_type(4))) float f32x4;

// ---------- bf16 helpers ----------
__device__ __forceinline__ float b2f(u16 u){ union { unsigned ui; float f; } v; v.ui = ((unsigned)u) << 16; return v.f; }
__device__ __forceinline__ u16 f2b(float f){ union { float f; unsigned ui; } v; v.f = f; unsigned r = (v.ui + 0x7FFF + ((v.ui >> 16) & 1)) >> 16; return (u16)r; }

// ---------- zero ----------
__global__ __launch_bounds__(256) void zero_f32(float* p, int n){
  int i = blockIdx.x*256 + threadIdx.x;
  if (i < n) p[i] = 0.f;
}

// ---------- transpose f32: W (KxN) -> Wt (NxK) ----------
__global__ __launch_bounds__(256) void transpose_f32(const float* __restrict__ W, float* __restrict__ Wt, int K, int N){
  __shared__ float tile[32][33];
  int bx = blockIdx.x * 32, by = blockIdx.y * 32;
  int tx = threadIdx.x & 31, ty = threadIdx.x >> 5;
  #pragma unroll
  for (int i = 0; i < 32; i += 8) tile[ty+i][tx] = W[(size_t)(by+ty+i)*N + bx+tx];
  __syncthreads();
  #pragma unroll
  for (int i = 0; i < 32; i += 8) Wt[(size_t)(bx+ty+i)*K + by+tx] = tile[tx][ty+i];
}

// ---------- transpose + downcast: W (KxN f32) -> Wt (NxK bf16) ----------
__global__ __launch_bounds__(256) void transpose_f2b(const float* __restrict__ W, u16* __restrict__ Wt, int K, int N){
  __shared__ u16 tile[32][33];
  int bx = blockIdx.x * 32, by = blockIdx.y * 32;
  int tx = threadIdx.x & 31, ty = threadIdx.x >> 5;
  #pragma unroll
  for (int i = 0; i < 32; i += 8) tile[ty+i][tx] = f2b(W[(size_t)(by+ty+i)*N + bx+tx]);
  __syncthreads();
  #pragma unroll
  for (int i = 0; i < 32; i += 8) Wt[(size_t)(bx+ty+i)*K + by+tx] = tile[tx][ty+i];
}

// ---------- split staging: 8 f32 -> up to 2 bf16 planes in LDS ----------
template<int NS>
__device__ __forceinline__ void stage_split(u16* lds, int off, const float* __restrict__ src){
  float v[8];
  *(float4*)v       = *(const float4*)src;
  *(float4*)(v + 4) = *(const float4*)(src + 4);
  u16 p0[8], p1[8];
  #pragma unroll
  for (int i = 0; i < 8; ++i){
    u16 a = f2b(v[i]); p0[i] = a;
    if constexpr (NS > 1){ p1[i] = f2b(v[i] - b2f(a)); }
  }
  *(uint4*)(lds + off) = *(uint4*)p0;
  if constexpr (NS > 1) *(uint4*)(lds + 4096 + off) = *(uint4*)p1;
}

// ---------- split GEMM: C = A(MxK f32) @ Bt(NxK f32)^T + bias ----------
// NPROD 3: 2-split (~1e-5 rel).  NPROD 1: plain bf16.
// MODE 0 epilogue: col<1024 -> Cq f32, col<2048 -> Ck f32, else Cv bf16.
template<int NPROD>
__global__ __launch_bounds__(256) void gemm_split(
    const float* __restrict__ A, int lda,
    const float* __restrict__ Bt, int bn_off,
    const float* __restrict__ bias,
    float* __restrict__ Cq, float* __restrict__ Ck, u16* __restrict__ Cv, int K)
{
  constexpr int NSA = (NPROD==3) ? 2 : 1;
  __shared__ __align__(16) u16 As[NSA*4096];
  __shared__ __align__(16) u16 Bs[NSA*4096];
  int tid = threadIdx.x, lane = tid & 63, wave = tid >> 6;
  int wm = wave >> 1, wn = wave & 1;
  int bm = blockIdx.y * 128, bn = blockIdx.x * 128;
  f32x4 acc[4][4];
  #pragma unroll
  for (int i=0;i<4;i++)
    #pragma unroll
    for (int j=0;j<4;j++)
      #pragma unroll
      for (int r=0;r<4;r++) acc[i][j][r] = 0.f;
  int mr = lane & 15, kq = (lane >> 4) * 8;
  for (int k0 = 0; k0 < K; k0 += 32) {
    #pragma unroll
    for (int v = 0; v < 2; ++v) {
      int idx = tid + v*256;
      int row = idx >> 2, col = (idx & 3) * 8;
      stage_split<NSA>(As, row*32 + col, &A [(size_t)(bm+row)*lda + k0 + col]);
      stage_split<NSA>(Bs, row*32 + col, &Bt[(size_t)(bn_off+bn+row)*K + k0 + col]);
    }
    __syncthreads();
    bfrag8 af[NSA][4], bf[NSA][4];
    #pragma unroll
    for (int s=0;s<NSA;s++){
      #pragma unroll
      for (int i=0;i<4;i++) af[s][i] = *(const bfrag8*)(&As[s*4096 + (wm*64 + i*16 + mr)*32 + kq]);
      #pragma unroll
      for (int j=0;j<4;j++) bf[s][j] = *(const bfrag8*)(&Bs[s*4096 + (wn*64 + j*16 + mr)*32 + kq]);
    }
#define MM(sa,sb) \
    { _Pragma("unroll") for (int i=0;i<4;i++){ _Pragma("unroll") for (int j=0;j<4;j++){ \
        acc[i][j] = __builtin_amdgcn_mfma_f32_16x16x32_bf16(af[sa][i], bf[sb][j], acc[i][j], 0, 0, 0); } } }
    if constexpr (NPROD == 3){ MM(0,1) MM(1,0) }
    MM(0,0)
#undef MM
    __syncthreads();
  }
  #pragma unroll
  for (int i=0;i<4;i++){
    #pragma unroll
    for (int j=0;j<4;j++){
      int col = bn_off + bn + wn*64 + j*16 + (lane & 15);
      float bv = bias[col];
      #pragma unroll
      for (int r=0;r<4;r++){
        int row = bm + wm*64 + i*16 + (lane>>4)*4 + r;
        float val = acc[i][j][r] + bv;
        if (col < 1024)      Cq[(size_t)row*1024 + col]        = val;
        else if (col < 2048) Ck[(size_t)row*1024 + (col-1024)] = val;
        else                 Cv[(size_t)row*1024 + (col-2048)] = f2b(val);
      }
    }
  }
}

// ---------- plain bf16 GEMM: C f32 = A(u16, lda) @ Bt(u16 NxK)^T + bias ----------
__global__ __launch_bounds__(256) void gemm_b16(const u16* __restrict__ A, int lda,
    const u16* __restrict__ Bt, const float* __restrict__ bias, float* __restrict__ C, int N, int K)
{
  __shared__ __align__(16) u16 As[4096];
  __shared__ __align__(16) u16 Bs[4096];
  int tid = threadIdx.x, lane = tid & 63, wave = tid >> 6;
  int wm = wave >> 1, wn = wave & 1;
  int bm = blockIdx.y * 128, bn = blockIdx.x * 128;
  f32x4 acc[4][4];
  #pragma unroll
  for (int i=0;i<4;i++)
    #pragma unroll
    for (int j=0;j<4;j++)
      #pragma unroll
      for (int r=0;r<4;r++) acc[i][j][r] = 0.f;
  int mr = lane & 15, kq = (lane >> 4) * 8;
  for (int k0 = 0; k0 < K; k0 += 32) {
    #pragma unroll
    for (int v = 0; v < 2; ++v) {
      int idx = tid + v*256;
      int row = idx >> 2, col = (idx & 3) * 8;
      *(uint4*)(&As[row*32 + col]) = *(const uint4*)(&A[(size_t)(bm+row)*lda + k0 + col]);
      *(uint4*)(&Bs[row*32 + col]) = *(const uint4*)(&Bt[(size_t)(bn+row)*K + k0 + col]);
    }
    __syncthreads();
    bfrag8 af[4], bf[4];
    #pragma unroll
    for (int i=0;i<4;i++) af[i] = *(const bfrag8*)(&As[(wm*64 + i*16 + mr)*32 + kq]);
    #pragma unroll
    for (int j=0;j<4;j++) bf[j] = *(const bfrag8*)(&Bs[(wn*64 + j*16 + mr)*32 + kq]);
    #pragma unroll
    for (int i=0;i<4;i++)
      #pragma unroll
      for (int j=0;j<4;j++)
        acc[i][j] = __builtin_amdgcn_mfma_f32_16x16x32_bf16(af[i], bf[j], acc[i][j], 0, 0, 0);
    __syncthreads();
  }
  #pragma unroll
  for (int i=0;i<4;i++){
    #pragma unroll
    for (int j=0;j<4;j++){
      int col = bn + wn*64 + j*16 + (lane & 15);
      float bv = bias[col];
      #pragma unroll
      for (int r=0;r<4;r++){
        int row = bm + wm*64 + i*16 + (lane>>4)*4 + r;
        C[(size_t)row*N + col] = acc[i][j][r] + bv;
      }
    }
  }
}

// ---------- per-d constants ----------
struct __align__(16) ConsT { int b1; float sg1; int b2; float sg2; };

// 4-lanes-per-token feature computation: tloc = lane&15 (token), g = lane>>4 (d-group).
// After this, every one of the 4 lanes holds full cs1/cs2/pm sums; poly4 = its 4 p's; prf = all 8.
#define FEATS_COMPUTE(TILE, TOKA)                                                \
  float sq = 0.f;                                                                \
  _Pragma("unroll")                                                              \
  for (int dd = 0; dd < 16; ++dd){ float u = TILE[(TOKA)*65 + g*16 + dd]; sq += u*u; } \
  sq += __shfl_xor(sq, 16); sq += __shfl_xor(sq, 32);                            \
  float sc = 1.f / fmaxf(sqrtf(sq), 1e-6f);                                      \
  float cs1[16], cs2[16], pm[8];                                                 \
  _Pragma("unroll") for (int p=0;p<16;p++){ cs1[p]=0.f; cs2[p]=0.f; }            \
  _Pragma("unroll") for (int m=0;m<8;m++) pm[m]=0.f;                             \
  _Pragma("unroll")                                                              \
  for (int dd = 0; dd < 16; ++dd){                                               \
    int d = g*16 + dd;                                                           \
    float un = TILE[(TOKA)*65 + d] * sc;                                         \
    ConsT cc = cons[d];                                                          \
    float v1 = un*cc.sg1, v2 = un*cc.sg2;                                        \
    _Pragma("unroll")                                                            \
    for (int p=0;p<16;p++){ cs1[p] += (cc.b1==p)?v1:0.f; cs2[p] += (cc.b2==p)?v2:0.f; } \
    _Pragma("unroll")                                                            \
    for (int m=0;m<8;m++) pm[m] += un * oms[d*8 + m];                            \
  }                                                                              \
  _Pragma("unroll")                                                              \
  for (int p=0;p<16;p++){ cs1[p] += __shfl_xor(cs1[p],16); cs1[p] += __shfl_xor(cs1[p],32); \
                          cs2[p] += __shfl_xor(cs2[p],16); cs2[p] += __shfl_xor(cs2[p],32); } \
  _Pragma("unroll")                                                              \
  for (int m=0;m<8;m++){ pm[m] += __shfl_xor(pm[m],16); pm[m] += __shfl_xor(pm[m],32); } \
  float poly4[4];                                                                \
  _Pragma("unroll")                                                              \
  for (int pi=0;pi<4;pi++){ int p = g*4 + pi; float s = 0.f;                     \
    _Pragma("unroll") for (int a=0;a<16;a++) s += cs1[a]*cs2[(p-a)&15];          \
    poly4[pi] = s * 0.25f; }                                                     \
  float prf[8];                                                                  \
  _Pragma("unroll")                                                              \
  for (int m=0;m<8;m++){ float e = fminf(fmaxf(pm[m]*sqrt2s - s_node, -10.f), 10.f); \
    prf[m] = expf(e) * pscale; }

// ---------- K-path: features + kv^T (64d x 128f) via MFMA + ksum ----------
__global__ __launch_bounds__(256) void kfeat_kv(const float* __restrict__ kf, const u16* __restrict__ vb,
    const float* __restrict__ omega, const float* __restrict__ qn, const float* __restrict__ qw,
    const int* __restrict__ h1, const int* __restrict__ s1,
    const int* __restrict__ h2, const int* __restrict__ s2,
    float* __restrict__ kvT, float* __restrict__ ksum)
{
  __shared__ float ktile[64*65];                 // 16.6 KB (f32 k, feature input)
  __shared__ __align__(16) u16 vtile[64*64];     //  8 KB  (bf16 V, [tok][d])
  __shared__ __align__(16) u16 featT[128*72];    // 18 KB  (bf16 feat^T, [f][tok])
  __shared__ float oms[64*8];
  __shared__ ConsT cons[64];
  int tid = threadIdx.x, lane = tid & 63, wave = tid >> 6;
  int bh = blockIdx.y, b = bh >> 4, h = bh & 15;
  int chunk = blockIdx.x;                        // 0..7, 512 tokens each
  if (tid < 64) {
    ConsT c; c.b1 = h1[tid]; c.sg1 = (float)s1[tid]; c.b2 = h2[tid]; c.sg2 = (float)s2[tid];
    cons[tid] = c;
  }
  for (int i = tid; i < 512; i += 256) oms[i] = omega[h*512 + i];
  float s_node = qn[0];
  float sqrt2s = sqrtf(2.f * fmaxf(s_node, 0.f));
  float pscale = 0.35355339059327373f * sqrtf(fmaxf(qw[0], 0.f));
  int tloc = lane & 15, g = lane >> 4;
  int tokA = wave*16 + tloc;
  int wm = wave >> 1, wn = wave & 1;             // MFMA wave grid: M=128f (2), N=64d (2)
  int mr = lane & 15, kq8 = (lane >> 4) * 8;
  f32x4 acc[4][2];                               // 4 m-frags x 2 n-frags
  #pragma unroll
  for (int i=0;i<4;i++)
    #pragma unroll
    for (int jn=0;jn<2;jn++)
      #pragma unroll
      for (int r=0;r<4;r++) acc[i][jn][r] = 0.f;
  float kacc[32];
  #pragma unroll
  for (int j=0;j<32;j++) kacc[j] = 0.f;
  for (int sub = 0; sub < 8; ++sub) {
    int base = chunk*512 + sub*64;
    __syncthreads();                             // prior MFMA reads done before tile overwrite
    for (int idx = tid; idx < 4096; idx += 256) {
      int t = idx >> 6, d = idx & 63;
      ktile[t*65 + d] = kf[(size_t)(b*4096 + base + t)*1024 + h*64 + d];
    }
    for (int slot = tid; slot < 512; slot += 256) {
      int t = slot >> 3, o = (slot & 7) * 8;
      *(uint4*)(&vtile[t*64 + o]) = *(const uint4*)(&vb[(size_t)(b*4096 + base + t)*1024 + h*64 + o]);
    }
    __syncthreads();                             // tiles ready
    {
      FEATS_COMPUTE(ktile, tokA)
      #pragma unroll
      for (int pi=0;pi<4;pi++){
        #pragma unroll
        for (int m=0;m<8;m++){
          int f = (g*4 + pi)*8 + m;
          float v = poly4[pi]*prf[m];
          featT[f*72 + tokA] = f2b(v);
          v += __shfl_xor(v,1); v += __shfl_xor(v,2); v += __shfl_xor(v,4); v += __shfl_xor(v,8);
          if (tloc == 0) kacc[pi*8 + m] += v;
        }
      }
    }
    __syncthreads();                             // featT ready
    #pragma unroll
    for (int k0 = 0; k0 < 64; k0 += 32) {
      bfrag8 af[4];
      #pragma unroll
      for (int i=0;i<4;i++) af[i] = *(const bfrag8*)(&featT[(wm*64 + i*16 + mr)*72 + k0 + kq8]);
      #pragma unroll
      for (int jn=0;jn<2;jn++){
        int d = wn*32 + jn*16 + mr;
        short tmp[8];
        #pragma unroll
        for (int j=0;j<8;j++) tmp[j] = (short)vtile[(k0 + kq8 + j)*64 + d];
        bfrag8 bf = *(bfrag8*)tmp;
        #pragma unroll
        for (int i=0;i<4;i++)
          acc[i][jn] = __builtin_amdgcn_mfma_f32_16x16x32_bf16(af[i], bf, acc[i][jn], 0, 0, 0);
      }
    }
  }
  // epilogue: kv^T[d][f] += acc   (C/D: col=lane&15, row=(lane>>4)*4+reg)
  #pragma unroll
  for (int i=0;i<4;i++){
    #pragma unroll
    for (int jn=0;jn<2;jn++){
      int d = wn*32 + jn*16 + (lane & 15);
      #pragma unroll
      for (int r=0;r<4;r++){
        int f = wm*64 + i*16 + (lane>>4)*4 + r;
        atomicAdd(&kvT[((size_t)bh*64 + d)*128 + f], acc[i][jn][r]);
      }
    }
  }
  if (tloc == 0){
    #pragma unroll
    for (int j=0;j<32;j++) atomicAdd(&ksum[bh*128 + g*32 + j], kacc[j]);
  }
}

// ---------- Q-path: features + nrm (f32) + ctx via MFMA; writes attn bf16 into kf region ----------
__global__ __launch_bounds__(256) void qfeat_ctx(const float* __restrict__ qf,
    const float* __restrict__ omega, const float* __restrict__ qn, const float* __restrict__ qw,
    const int* __restrict__ h1, const int* __restrict__ s1,
    const int* __restrict__ h2, const int* __restrict__ s2,
    const float* __restrict__ kvT, const float* __restrict__ ksum,
    u16* __restrict__ attn)                      // row stride 2048 u16 (kf reuse)
{
  __shared__ float qtile[64*65];                 // 16.6 KB
  __shared__ __align__(16) u16 feat[64*136];     // 17.4 KB [tok][f]
  __shared__ __align__(16) u16 kvsb0[64*136];    // 17.4 KB [d][f] split-hi
  __shared__ __align__(16) u16 kvsb1[64*136];    // 17.4 KB [d][f] split-lo
  __shared__ float ksums[128];
  __shared__ float nrm_s[64];
  __shared__ float oms[64*8];
  __shared__ ConsT cons[64];
  int tid = threadIdx.x, lane = tid & 63, wave = tid >> 6;
  int bh = blockIdx.y, b = bh >> 4, h = bh & 15;
  int chunk = blockIdx.x;                        // 0..7, 512 tokens each
  if (tid < 64) {
    ConsT c; c.b1 = h1[tid]; c.sg1 = (float)s1[tid]; c.b2 = h2[tid]; c.sg2 = (float)s2[tid];
    cons[tid] = c;
  }
  for (int i = tid; i < 512; i += 256) oms[i] = omega[h*512 + i];
  for (int idx = tid; idx < 8192; idx += 256) {
    int d = idx >> 7, f = idx & 127;
    float v = kvT[((size_t)bh*64 + d)*128 + f];
    u16 b0 = f2b(v);
    kvsb0[d*136 + f] = b0;
    kvsb1[d*136 + f] = f2b(v - b2f(b0));
  }
  if (tid < 128) ksums[tid] = ksum[bh*128 + tid];
  float s_node = qn[0];
  float sqrt2s = sqrtf(2.f * fmaxf(s_node, 0.f));
  float pscale = 0.35355339059327373f * sqrtf(fmaxf(qw[0], 0.f));
  int tloc = lane & 15, g = lane >> 4;
  int tokA = wave*16 + tloc;
  int mr = lane & 15, kq8 = (lane >> 4) * 8;
  for (int sub = 0; sub < 8; ++sub) {
    int base = chunk*512 + sub*64;
    for (int idx = tid; idx < 4096; idx += 256) {
      int t = idx >> 6, d = idx & 63;
      qtile[t*65 + d] = qf[(size_t)(b*4096 + base + t)*1024 + h*64 + d];
    }
    __syncthreads();                             // qtile ready; prior MFMA feat reads done
    {
      FEATS_COMPUTE(qtile, tokA)
      float nv = 0.f;
      #pragma unroll
      for (int pi=0;pi<4;pi++){
        #pragma unroll
        for (int m=0;m<8;m++){
          int f = (g*4 + pi)*8 + m;
          float v = poly4[pi]*prf[m];
          feat[tokA*136 + f] = f2b(v);
          nv += v * ksums[f];
        }
      }
      nv += __shfl_xor(nv, 16); nv += __shfl_xor(nv, 32);
      if (lane < 16) nrm_s[tokA] = nv;
    }
    __syncthreads();                             // feat + nrm ready
    // ctx(16tok x 64d per wave) = feat @ kv  (kv 2-split)
    f32x4 cacc[4];
    #pragma unroll
    for (int jn=0;jn<4;jn++)
      #pragma unroll
      for (int r=0;r<4;r++) cacc[jn][r] = 0.f;
    #pragma unroll
    for (int k0 = 0; k0 < 128; k0 += 32) {
      bfrag8 af = *(const bfrag8*)(&feat[(wave*16 + mr)*136 + k0 + kq8]);
      #pragma unroll
      for (int jn=0;jn<4;jn++){
        int d = jn*16 + mr;
        bfrag8 b0 = *(const bfrag8*)(&kvsb0[d*136 + k0 + kq8]);
        cacc[jn] = __builtin_amdgcn_mfma_f32_16x16x32_bf16(af, b0, cacc[jn], 0, 0, 0);
        bfrag8 b1 = *(const bfrag8*)(&kvsb1[d*136 + k0 + kq8]);
        cacc[jn] = __builtin_amdgcn_mfma_f32_16x16x32_bf16(af, b1, cacc[jn], 0, 0, 0);
      }
    }
    #pragma unroll
    for (int jn=0;jn<4;jn++){
      int d = jn*16 + (lane & 15);
      #pragma unroll
      for (int r=0;r<4;r++){
        int row = (lane>>4)*4 + r;
        float nrm = nrm_s[wave*16 + row];
        int tok = base + wave*16 + row;
        attn[(size_t)(b*4096 + tok)*2048 + h*64 + d] = f2b(cacc[jn][r] / fmaxf(nrm, 1e-4f));
      }
    }
  }
}

// ---------- launch ----------
extern "C" void kernel_launch(void* const* d_in, const int* in_sizes, int n_in,
                              void* d_out, int out_size, void* d_ws, size_t ws_size,
                              hipStream_t stream)
{
  const float* x     = (const float*)d_in[0];
  const float* qkv_w = (const float*)d_in[1];
  const float* qkv_b = (const float*)d_in[2];
  const float* out_w = (const float*)d_in[3];
  const float* out_b = (const float*)d_in[4];
  const float* omega = (const float*)d_in[5];
  const float* qn    = (const float*)d_in[6];
  const float* qw    = (const float*)d_in[7];
  const int* h1 = (const int*)d_in[8];
  const int* s1 = (const int*)d_in[9];
  const int* h2 = (const int*)d_in[10];
  const int* s2 = (const int*)d_in[11];

  // ws (~176 MB): qf f32 | kf f32 (later attn bf16, lda 2048) | vb bf16 | wT1 f32 | wT2 bf16 | kvT f32 | ksum f32
  const size_t SZ_Q   = (size_t)16384*1024*4;   // 64 MB
  const size_t SZ_K   = (size_t)16384*1024*4;   // 64 MB
  const size_t SZ_V   = (size_t)16384*1024*2;   // 32 MB
  const size_t SZ_WT1 = (size_t)3072*1024*4;    // 12 MB
  const size_t SZ_WT2 = (size_t)1024*1024*2;    //  2 MB
  const size_t SZ_KV  = (size_t)64*64*128*4;    //  2 MB
  char* ws = (char*)d_ws;
  float* qf  = (float*)ws;
  float* kf  = (float*)(ws + SZ_Q);
  u16*   vb  = (u16*)  (ws + SZ_Q + SZ_K);
  float* wT1 = (float*)(ws + SZ_Q + SZ_K + SZ_V);
  u16*   wT2 = (u16*)  (ws + SZ_Q + SZ_K + SZ_V + SZ_WT1);
  float* kvT = (float*)(ws + SZ_Q + SZ_K + SZ_V + SZ_WT1 + SZ_WT2);
  float* ksp = (float*)(ws + SZ_Q + SZ_K + SZ_V + SZ_WT1 + SZ_WT2 + SZ_KV);

  int nz = (int)((SZ_KV + (size_t)64*128*4) / 4);
  zero_f32<<<(nz+255)/256, 256, 0, stream>>>(kvT, nz);
  transpose_f32<<<dim3(3072/32, 1024/32), 256, 0, stream>>>(qkv_w, wT1, 1024, 3072);
  transpose_f2b<<<dim3(1024/32, 1024/32), 256, 0, stream>>>(out_w, wT2, 1024, 1024);
  // q,k (cols 0..2047): 2-split, 3 products
  gemm_split<3><<<dim3(16, 128), 256, 0, stream>>>(x, 1024, wT1, 0, qkv_b, qf, kf, vb, 1024);
  // v (cols 2048..3071): plain bf16
  gemm_split<1><<<dim3(8, 128), 256, 0, stream>>>(x, 1024, wT1, 2048, qkv_b, qf, kf, vb, 1024);
  kfeat_kv<<<dim3(8, 64), 256, 0, stream>>>(kf, vb, omega, qn, qw, h1, s1, h2, s2, kvT, ksp);
  qfeat_ctx<<<dim3(8, 64), 256, 0, stream>>>(qf, omega, qn, qw, h1, s1, h2, s2, kvT, ksp, (u16*)kf);
  // out = attn @ out_w + out_b (plain bf16; attn rows have stride 2048 u16)
  gemm_b16<<<dim3(8, 128), 256, 0, stream>>>((const u16*)kf, 2048, wT2, out_b, (float*)d_out, 1024, 1024);
}